// Round 1
// baseline (450.744 us; speedup 1.0000x reference)
//
#include <hip/hip_runtime.h>

// Problem constants
#define B_    64
#define C_    3
#define H_    384
#define W_    384
#define P_    16
#define E_    768
#define N_    576                 // patches per image
#define M_    (B_ * N_)           // 36864 total patches
#define K_    (C_ * P_ * P_)      // 768 reduction dim

// Tiling
#define BM    128
#define BN    128
#define BK    32
#define AST   40                  // LDS row stride in bf16 elems (32 + 8 pad -> 80B rows, 2-way bank alias = free)

typedef __attribute__((ext_vector_type(8))) short  short8;   // bf16x8 MFMA operand (4 VGPRs)
typedef __attribute__((ext_vector_type(4))) float  f32x4;    // MFMA accumulator

// round-to-nearest-even f32 -> bf16 bits
__device__ __forceinline__ unsigned short f2bf(float f) {
    unsigned int u = __float_as_uint(f);
    u += 0x7FFFu + ((u >> 16) & 1u);
    return (unsigned short)(u >> 16);
}

__global__ __launch_bounds__(256, 2)
void patch_embed_gemm(const float* __restrict__ x,
                      const int*   __restrict__ ys,
                      const int*   __restrict__ xs,
                      const float* __restrict__ w,
                      const float* __restrict__ bias,
                      float*       __restrict__ out)
{
    __shared__ unsigned short Asm[BM * AST];   // 128 x (32+8) bf16 = 10 KB
    __shared__ unsigned short Bsm[BN * AST];   // 10 KB

    const int t  = threadIdx.x;          // 0..255
    const int m0 = blockIdx.x * BM;      // patch-tile origin
    const int e0 = blockIdx.y * BN;      // embed-tile origin

    // ---- staging roles: 2 threads per LDS row (one 16-px image row each) ----
    const int sp   = t >> 1;             // 0..127: row within tile
    const int half = t & 1;              // which of the 2 image rows in this BK chunk

    // A-side gather setup (per-thread, loop-invariant)
    const int m    = m0 + sp;            // global patch id; ys/xs are [B,N] flat = [m]
    const int bimg = m / N_;
    const int y    = ys[m];
    const int xx   = xs[m];
    const float* abase = x + (size_t)bimg * (C_ * H_ * W_) + (size_t)(y + half) * W_ + xx;

    // B-side setup: w is [E][K] row-major; we want Bsm[e_local][k] (B^T layout)
    const float* wbase = w + (size_t)(e0 + sp) * K_ + half * 16;

    // ---- compute roles ----
    const int wave = t >> 6;             // 4 waves: 2x2 of 64x64 subtiles
    const int lane = t & 63;
    const int wr   = (wave >> 1) * 64;   // wave row offset (M)
    const int wc   = (wave & 1) * 64;    // wave col offset (E)
    const int lm   = lane & 15;
    const int quad = lane >> 4;

    f32x4 acc[4][4];
#pragma unroll
    for (int i = 0; i < 4; ++i)
#pragma unroll
        for (int j = 0; j < 4; ++j)
            acc[i][j] = (f32x4){0.f, 0.f, 0.f, 0.f};

#pragma unroll 1
    for (int it = 0; it < K_ / BK; ++it) {
        // BK=32 chunk = channel c = it>>3, image rows py0, py0+1 (never crosses channel)
        const int c   = it >> 3;
        const int py0 = (it & 7) * 2;

        // ---- gather A: 16 consecutive floats of one patch row (4B-aligned only) ----
        const float* src = abase + (size_t)c * (H_ * W_) + (size_t)py0 * W_;
        union { unsigned short us[16]; uint4 q[2]; } pa;
#pragma unroll
        for (int j = 0; j < 16; ++j) pa.us[j] = f2bf(src[j]);

        // ---- load B: 16 consecutive floats of w row (64B-aligned -> float4) ----
        const float4* bs = (const float4*)(wbase + it * BK);
        union { unsigned short us[16]; uint4 q[2]; } pb;
#pragma unroll
        for (int j = 0; j < 4; ++j) {
            float4 f = bs[j];
            pb.us[4 * j + 0] = f2bf(f.x);
            pb.us[4 * j + 1] = f2bf(f.y);
            pb.us[4 * j + 2] = f2bf(f.z);
            pb.us[4 * j + 3] = f2bf(f.w);
        }

        // ---- LDS writes (16B-aligned: row stride 80B, half*32B) ----
        *(uint4*)&Asm[sp * AST + half * 16]     = pa.q[0];
        *(uint4*)&Asm[sp * AST + half * 16 + 8] = pa.q[1];
        *(uint4*)&Bsm[sp * AST + half * 16]     = pb.q[0];
        *(uint4*)&Bsm[sp * AST + half * 16 + 8] = pb.q[1];

        __syncthreads();

        // ---- MFMA: A[m=lane&15][k=quad*8+j], B[k=quad*8+j][n=lane&15] ----
        short8 af[4], bf[4];
#pragma unroll
        for (int i = 0; i < 4; ++i)
            af[i] = *(const short8*)&Asm[(wr + i * 16 + lm) * AST + quad * 8];
#pragma unroll
        for (int i = 0; i < 4; ++i)
            bf[i] = *(const short8*)&Bsm[(wc + i * 16 + lm) * AST + quad * 8];

#pragma unroll
        for (int i = 0; i < 4; ++i)
#pragma unroll
            for (int j = 0; j < 4; ++j)
                acc[i][j] = __builtin_amdgcn_mfma_f32_16x16x32_bf16(af[i], bf[j], acc[i][j], 0, 0, 0);

        __syncthreads();
    }

    // ---- epilogue: C/D layout col=lane&15, row=quad*4+reg (m89-verified) ----
    float bv[4];
#pragma unroll
    for (int j = 0; j < 4; ++j) bv[j] = bias[e0 + wc + j * 16 + lm];

#pragma unroll
    for (int i = 0; i < 4; ++i) {
#pragma unroll
        for (int j = 0; j < 4; ++j) {
            const int eo = e0 + wc + j * 16 + lm;
#pragma unroll
            for (int r = 0; r < 4; ++r) {
                const int mo = m0 + wr + i * 16 + quad * 4 + r;
                out[(size_t)mo * E_ + eo] = acc[i][j][r] + bv[j];
            }
        }
    }
}

__global__ void pos_kernel(const int* __restrict__ ys, const int* __restrict__ xs,
                           float* __restrict__ outp)
{
    int i = blockIdx.x * blockDim.x + threadIdx.x;
    if (i < M_) {
        outp[2 * i]     = (float)ys[i];   // patch_positions[...,0] = ys
        outp[2 * i + 1] = (float)xs[i];   // patch_positions[...,1] = xs
    }
}

extern "C" void kernel_launch(void* const* d_in, const int* in_sizes, int n_in,
                              void* d_out, int out_size, void* d_ws, size_t ws_size,
                              hipStream_t stream)
{
    const float* x    = (const float*)d_in[0];
    const int*   ys   = (const int*)d_in[1];
    const int*   xs   = (const int*)d_in[2];
    const float* w    = (const float*)d_in[3];
    const float* bias = (const float*)d_in[4];
    float* out = (float*)d_out;

    dim3 grid(M_ / BM, E_ / BN);   // 288 x 6
    patch_embed_gemm<<<grid, 256, 0, stream>>>(x, ys, xs, w, bias, out);

    float* outp = out + (size_t)M_ * E_;   // positions follow tokens, flat
    pos_kernel<<<(M_ + 255) / 256, 256, 0, stream>>>(ys, xs, outp);
}

// Round 2
// 280.002 us; speedup vs baseline: 1.6098x; 1.6098x over previous
//
#include <hip/hip_runtime.h>

// Problem constants
#define B_    64
#define C_    3
#define H_    384
#define W_    384
#define P_    16
#define E_    768
#define N_    576                 // patches per image
#define M_    (B_ * N_)           // 36864 total patches
#define K_    (C_ * P_ * P_)      // 768 reduction dim

// GEMM tiling (m97 structure)
#define BM    128
#define BN    128
#define BK    32

typedef __attribute__((ext_vector_type(8))) short  short8;   // bf16x8 MFMA operand
typedef __attribute__((ext_vector_type(4))) float  f32x4;    // MFMA accumulator

// round-to-nearest-even f32 -> bf16 bits
__device__ __forceinline__ unsigned short f2bf(float f) {
    unsigned int u = __float_as_uint(f);
    u += 0x7FFFu + ((u >> 16) & 1u);
    return (unsigned short)(u >> 16);
}

// async global->LDS, 16B per lane (global_load_lds_dwordx4)
__device__ __forceinline__ void gload_lds16(const void* g, void* l) {
    __builtin_amdgcn_global_load_lds(
        (const __attribute__((address_space(1))) unsigned int*)g,
        (__attribute__((address_space(3))) unsigned int*)l,
        16, 0, 0);
}

// ---------------------------------------------------------------------------
// Phase 1: gather patches -> contiguous bf16 A[M][768] in workspace.
// 192 threads per patch: (c, py, q) with q = 16B quarter of a 16-px row.
// Lanes q=0..3 of a row read 16 consecutive dwords -> coalesced segments.
// Writes: thread g writes 8B at byte offset g*8 -> perfectly coalesced.
// ---------------------------------------------------------------------------
__global__ __launch_bounds__(256)
void gather_kernel(const float* __restrict__ x,
                   const int*   __restrict__ ys,
                   const int*   __restrict__ xs,
                   unsigned short* __restrict__ Abf)
{
    const unsigned g = blockIdx.x * 256 + threadIdx.x;   // < M_*192
    const unsigned patch = g / 192u;
    const unsigned r  = g - patch * 192u;                // 0..191
    const unsigned c  = r >> 6;                          // channel 0..2
    const unsigned r2 = r & 63u;
    const unsigned py = r2 >> 2;                         // row in patch 0..15
    const unsigned q  = r2 & 3u;                         // 4-float quarter

    const unsigned bimg = patch / (unsigned)N_;
    const int y  = ys[patch];
    const int xx = xs[patch];

    const float* src = x + (size_t)bimg * (C_ * H_ * W_)
                         + (size_t)c * (H_ * W_)
                         + (size_t)(y + py) * W_ + xx + q * 4;

    uint2 pk;
    pk.x = (unsigned)f2bf(src[0]) | ((unsigned)f2bf(src[1]) << 16);
    pk.y = (unsigned)f2bf(src[2]) | ((unsigned)f2bf(src[3]) << 16);
    // dest elem offset = patch*768 + c*256 + py*16 + q*4 == g*4
    *(uint2*)(Abf + (size_t)g * 4) = pk;
}

// Phase 1b: w [E][K] fp32 -> bf16 (B^T layout already)
__global__ __launch_bounds__(256)
void wconv_kernel(const float* __restrict__ w, unsigned short* __restrict__ Wb)
{
    const unsigned g = blockIdx.x * 256 + threadIdx.x;   // < E_*K_/4
    float4 f = ((const float4*)w)[g];
    uint2 pk;
    pk.x = (unsigned)f2bf(f.x) | ((unsigned)f2bf(f.y) << 16);
    pk.y = (unsigned)f2bf(f.z) | ((unsigned)f2bf(f.w) << 16);
    *(uint2*)(Wb + (size_t)g * 4) = pk;
}

// ---------------------------------------------------------------------------
// Phase 2: m97-style GEMM. A[M,768] bf16, B=Wb[E,768] bf16 (B^T), out fp32.
// 128x128 tile, BK=32, 4 waves (2x2 of 64x64), global_load_lds staging.
// LDS tiles contiguous [128][32] bf16 (no pad -- global_load_lds needs
// wave-uniform base + lane*16 contiguity).
// ---------------------------------------------------------------------------
__global__ void gemm_bf16(const unsigned short* __restrict__ A,
                          const unsigned short* __restrict__ Wb,
                          const float* __restrict__ bias,
                          float*       __restrict__ out)
{
    __shared__ unsigned short Asm[BM * BK];   // 8 KB
    __shared__ unsigned short Bsm[BN * BK];   // 8 KB

    const int t    = threadIdx.x;
    const int e0   = blockIdx.x * BN;   // fast dim: 6 e-tiles of one m-tile adjacent
    const int m0   = blockIdx.y * BM;
    const int wave = t >> 6;
    const int lane = t & 63;

    // staging: wave stages rows [wave*32, wave*32+32) of both tiles;
    // per instruction 16 rows: row = wave*32 + i*16 + lane/4, 16B chunk = lane&3
    const int srow = wave * 32 + (lane >> 2);
    const int scol = (lane & 3) * 8;                    // bf16 elems
    const unsigned short* Ag = A  + (size_t)(m0 + srow) * K_ + scol;
    const unsigned short* Bg = Wb + (size_t)(e0 + srow) * K_ + scol;
    unsigned short* Al = &Asm[srow * BK + scol];        // = wavebase + lane*16 B
    unsigned short* Bl = &Bsm[srow * BK + scol];

    // compute roles
    const int wr   = (wave >> 1) * 64;
    const int wc   = (wave & 1) * 64;
    const int lm   = lane & 15;
    const int quad = lane >> 4;

    f32x4 acc[4][4];
#pragma unroll
    for (int i = 0; i < 4; ++i)
#pragma unroll
        for (int j = 0; j < 4; ++j)
            acc[i][j] = (f32x4){0.f, 0.f, 0.f, 0.f};

#pragma unroll 1
    for (int it = 0; it < K_ / BK; ++it) {
        const unsigned short* ag = Ag + it * BK;
        const unsigned short* bg = Bg + it * BK;
        gload_lds16(ag,           Al);
        gload_lds16(ag + 16 * K_, Al + 16 * BK);
        gload_lds16(bg,           Bl);
        gload_lds16(bg + 16 * K_, Bl + 16 * BK);

        __syncthreads();   // drains vmcnt (global_load_lds) before use

        short8 af[4], bfr[4];
#pragma unroll
        for (int i = 0; i < 4; ++i)
            af[i] = *(const short8*)&Asm[(wr + i * 16 + lm) * BK + quad * 8];
#pragma unroll
        for (int j = 0; j < 4; ++j)
            bfr[j] = *(const short8*)&Bsm[(wc + j * 16 + lm) * BK + quad * 8];

#pragma unroll
        for (int i = 0; i < 4; ++i)
#pragma unroll
            for (int j = 0; j < 4; ++j)
                acc[i][j] = __builtin_amdgcn_mfma_f32_16x16x32_bf16(af[i], bfr[j], acc[i][j], 0, 0, 0);

        __syncthreads();
    }

    // epilogue: C/D layout col=lane&15, row=quad*4+reg (m89-verified)
    float bv[4];
#pragma unroll
    for (int j = 0; j < 4; ++j) bv[j] = bias[e0 + wc + j * 16 + lm];

#pragma unroll
    for (int i = 0; i < 4; ++i) {
#pragma unroll
        for (int j = 0; j < 4; ++j) {
            const int eo = e0 + wc + j * 16 + lm;
#pragma unroll
            for (int r = 0; r < 4; ++r) {
                const int mo = m0 + wr + i * 16 + quad * 4 + r;
                out[(size_t)mo * E_ + eo] = acc[i][j][r] + bv[j];
            }
        }
    }
}

__global__ void pos_kernel(const int* __restrict__ ys, const int* __restrict__ xs,
                           float* __restrict__ outp)
{
    int i = blockIdx.x * blockDim.x + threadIdx.x;
    if (i < M_) {
        outp[2 * i]     = (float)ys[i];
        outp[2 * i + 1] = (float)xs[i];
    }
}

extern "C" void kernel_launch(void* const* d_in, const int* in_sizes, int n_in,
                              void* d_out, int out_size, void* d_ws, size_t ws_size,
                              hipStream_t stream)
{
    const float* x    = (const float*)d_in[0];
    const int*   ys   = (const int*)d_in[1];
    const int*   xs   = (const int*)d_in[2];
    const float* w    = (const float*)d_in[3];
    const float* bias = (const float*)d_in[4];
    float* out = (float*)d_out;

    // workspace layout: A_bf16 [M][768] then W_bf16 [E][768]
    unsigned short* Abf = (unsigned short*)d_ws;
    unsigned short* Wb  = Abf + (size_t)M_ * K_;   // offset 56,623,104 B (16B aligned)

    gather_kernel<<<(M_ * 192) / 256, 256, 0, stream>>>(x, ys, xs, Abf);
    wconv_kernel<<<(E_ * K_ / 4) / 256, 256, 0, stream>>>(w, Wb);

    dim3 grid(E_ / BN, M_ / BM);   // (6, 288): e-tile fastest for A-slab L2/L3 reuse
    gemm_bf16<<<grid, 256, 0, stream>>>(Abf, Wb, bias, out);

    float* outp = out + (size_t)M_ * E_;
    pos_kernel<<<(M_ + 255) / 256, 256, 0, stream>>>(ys, xs, outp);
}

// Round 3
// 273.267 us; speedup vs baseline: 1.6495x; 1.0246x over previous
//
#include <hip/hip_runtime.h>

// Problem constants
#define B_    64
#define C_    3
#define H_    384
#define W_    384
#define P_    16
#define E_    768
#define N_    576                 // patches per image
#define M_    (B_ * N_)           // 36864 total patches
#define K_    (C_ * P_ * P_)      // 768 reduction dim

// GEMM tiling
#define BM    128
#define BN    128
#define BK    64                  // 12 K-iters: half the barrier drains of BK=32

typedef __attribute__((ext_vector_type(8))) short  short8;   // bf16x8 MFMA operand
typedef __attribute__((ext_vector_type(4))) float  f32x4;    // MFMA accumulator

// round-to-nearest-even f32 -> bf16 bits
__device__ __forceinline__ unsigned short f2bf(float f) {
    unsigned int u = __float_as_uint(f);
    u += 0x7FFFu + ((u >> 16) & 1u);
    return (unsigned short)(u >> 16);
}

// async global->LDS, 16B per lane (global_load_lds_dwordx4)
__device__ __forceinline__ void gload_lds16(const void* g, void* l) {
    __builtin_amdgcn_global_load_lds(
        (const __attribute__((address_space(1))) unsigned int*)g,
        (__attribute__((address_space(3))) unsigned int*)l,
        16, 0, 0);
}

// ---------------------------------------------------------------------------
// Phase 1: gather patches -> contiguous bf16 A[M][768] in workspace.
// ---------------------------------------------------------------------------
__global__ __launch_bounds__(256)
void gather_kernel(const float* __restrict__ x,
                   const int*   __restrict__ ys,
                   const int*   __restrict__ xs,
                   unsigned short* __restrict__ Abf)
{
    const unsigned g = blockIdx.x * 256 + threadIdx.x;   // < M_*192
    const unsigned patch = g / 192u;
    const unsigned r  = g - patch * 192u;                // 0..191
    const unsigned c  = r >> 6;                          // channel 0..2
    const unsigned r2 = r & 63u;
    const unsigned py = r2 >> 2;                         // row in patch 0..15
    const unsigned q  = r2 & 3u;                         // 4-float quarter

    const unsigned bimg = patch / (unsigned)N_;
    const int y  = ys[patch];
    const int xx = xs[patch];

    const float* src = x + (size_t)bimg * (C_ * H_ * W_)
                         + (size_t)c * (H_ * W_)
                         + (size_t)(y + py) * W_ + xx + q * 4;

    uint2 pk;
    pk.x = (unsigned)f2bf(src[0]) | ((unsigned)f2bf(src[1]) << 16);
    pk.y = (unsigned)f2bf(src[2]) | ((unsigned)f2bf(src[3]) << 16);
    *(uint2*)(Abf + (size_t)g * 4) = pk;    // dest offset = g*4 elems
}

// Phase 1b: w [E][K] fp32 -> bf16 (B^T layout already)
__global__ __launch_bounds__(256)
void wconv_kernel(const float* __restrict__ w, unsigned short* __restrict__ Wb)
{
    const unsigned g = blockIdx.x * 256 + threadIdx.x;   // < E_*K_/4
    float4 f = ((const float4*)w)[g];
    uint2 pk;
    pk.x = (unsigned)f2bf(f.x) | ((unsigned)f2bf(f.y) << 16);
    pk.y = (unsigned)f2bf(f.z) | ((unsigned)f2bf(f.w) << 16);
    *(uint2*)(Wb + (size_t)g * 4) = pk;
}

// ---------------------------------------------------------------------------
// Phase 2: GEMM. A[M,768] bf16, B=Wb[E,768] bf16 (B^T), out fp32 + bias.
// 128x128x64 tile, 4 waves (2x2 of 64x64), global_load_lds width-16 staging.
// XCD swizzle: the 6 e-tiles sharing an A-slab get the same (b&7) so they
// land on one XCD's L2 under round-robin dispatch.
// ---------------------------------------------------------------------------
__global__ __launch_bounds__(256)
void gemm_bf16(const unsigned short* __restrict__ A,
               const unsigned short* __restrict__ Wb,
               const float* __restrict__ bias,
               float*       __restrict__ out)
{
    __shared__ unsigned short Asm[BM * BK];   // 16 KB
    __shared__ unsigned short Bsm[BN * BK];   // 16 KB

    const int t    = threadIdx.x;
    const int wave = t >> 6;
    const int lane = t & 63;

    // XCD-aware swizzle: 1728 blocks = 8 xcd-groups x 36 m-tiles x 6 e-tiles
    const int b   = blockIdx.x;
    const int xcd = b & 7;
    const int idx = b >> 3;              // 0..215
    const int mt  = xcd * 36 + idx / 6;  // m-tile 0..287 (same for 6 consecutive idx)
    const int et  = idx % 6;
    const int m0  = mt * BM;
    const int e0  = et * BN;

    // staging: wave stages rows [wave*32, wave*32+32); per instruction 8 rows,
    // lane -> row wave*32 + inst*8 + (lane>>3), 16B chunk (lane&7)
    const int r8 = lane >> 3;            // 0..7
    const int c8 = (lane & 7) * 8;       // bf16 elem col (0..56 step 8)
    const unsigned short* Ag = A  + (size_t)(m0 + wave * 32 + r8) * K_ + c8;
    const unsigned short* Bg = Wb + (size_t)(e0 + wave * 32 + r8) * K_ + c8;
    unsigned short* Al = &Asm[(wave * 32 + r8) * BK + c8];  // = wavebase + lane*16B
    unsigned short* Bl = &Bsm[(wave * 32 + r8) * BK + c8];

    // compute roles
    const int wr   = (wave >> 1) * 64;
    const int wc   = (wave & 1) * 64;
    const int lm   = lane & 15;
    const int quad = lane >> 4;

    f32x4 acc[4][4];
#pragma unroll
    for (int i = 0; i < 4; ++i)
#pragma unroll
        for (int j = 0; j < 4; ++j)
            acc[i][j] = (f32x4){0.f, 0.f, 0.f, 0.f};

#pragma unroll 1
    for (int it = 0; it < K_ / BK; ++it) {
        const unsigned short* ag = Ag + it * BK;
        const unsigned short* bg = Bg + it * BK;
#pragma unroll
        for (int inst = 0; inst < 4; ++inst) {   // 8 rows per instruction
            gload_lds16(ag + (size_t)(inst * 8) * K_, Al + inst * 8 * BK);
            gload_lds16(bg + (size_t)(inst * 8) * K_, Bl + inst * 8 * BK);
        }

        __syncthreads();   // drains vmcnt before LDS use

#pragma unroll
        for (int s = 0; s < 2; ++s) {            // two K=32 sub-steps
            short8 af[4], bfr[4];
#pragma unroll
            for (int i = 0; i < 4; ++i)
                af[i] = *(const short8*)&Asm[(wr + i * 16 + lm) * BK + s * 32 + quad * 8];
#pragma unroll
            for (int j = 0; j < 4; ++j)
                bfr[j] = *(const short8*)&Bsm[(wc + j * 16 + lm) * BK + s * 32 + quad * 8];
#pragma unroll
            for (int i = 0; i < 4; ++i)
#pragma unroll
                for (int j = 0; j < 4; ++j)
                    acc[i][j] = __builtin_amdgcn_mfma_f32_16x16x32_bf16(af[i], bfr[j], acc[i][j], 0, 0, 0);
        }

        __syncthreads();
    }

    // epilogue: C/D layout col=lane&15, row=quad*4+reg (m89-verified)
    float bv[4];
#pragma unroll
    for (int j = 0; j < 4; ++j) bv[j] = bias[e0 + wc + j * 16 + lm];

#pragma unroll
    for (int i = 0; i < 4; ++i) {
#pragma unroll
        for (int j = 0; j < 4; ++j) {
            const int eo = e0 + wc + j * 16 + lm;
#pragma unroll
            for (int r = 0; r < 4; ++r) {
                const int mo = m0 + wr + i * 16 + quad * 4 + r;
                out[(size_t)mo * E_ + eo] = acc[i][j][r] + bv[j];
            }
        }
    }
}

__global__ void pos_kernel(const int* __restrict__ ys, const int* __restrict__ xs,
                           float* __restrict__ outp)
{
    int i = blockIdx.x * blockDim.x + threadIdx.x;
    if (i < M_) {
        outp[2 * i]     = (float)ys[i];
        outp[2 * i + 1] = (float)xs[i];
    }
}

extern "C" void kernel_launch(void* const* d_in, const int* in_sizes, int n_in,
                              void* d_out, int out_size, void* d_ws, size_t ws_size,
                              hipStream_t stream)
{
    const float* x    = (const float*)d_in[0];
    const int*   ys   = (const int*)d_in[1];
    const int*   xs   = (const int*)d_in[2];
    const float* w    = (const float*)d_in[3];
    const float* bias = (const float*)d_in[4];
    float* out = (float*)d_out;

    // workspace layout: A_bf16 [M][768] then W_bf16 [E][768]
    unsigned short* Abf = (unsigned short*)d_ws;
    unsigned short* Wb  = Abf + (size_t)M_ * K_;

    gather_kernel<<<(M_ * 192) / 256, 256, 0, stream>>>(x, ys, xs, Abf);
    wconv_kernel<<<(E_ * K_ / 4) / 256, 256, 0, stream>>>(w, Wb);

    gemm_bf16<<<(M_ / BM) * (E_ / BN), 256, 0, stream>>>(Abf, Wb, bias, out);

    float* outp = out + (size_t)M_ * E_;
    pos_kernel<<<(M_ + 255) / 256, 256, 0, stream>>>(ys, xs, outp);
}